// Round 1
// baseline (2928.259 us; speedup 1.0000x reference)
//
#include <hip/hip_runtime.h>

#define D 128
#define TM 64
#define LDK 132   // 128 + 4 pad: row-to-row bank shift of 4

// ---------------- K1: edge scatter-add ----------------
// 32 lanes per edge; each lane loads a float4 of h[src] and does 4 atomic adds
// into out[dst]. out must be pre-zeroed.
__global__ __launch_bounds__(256) void scatter_kernel(
    const float* __restrict__ h, const int* __restrict__ esrc,
    const int* __restrict__ edst, float* __restrict__ out, int n_edges)
{
    int gid = blockIdx.x * 256 + threadIdx.x;
    int e = gid >> 5;
    int l = gid & 31;
    if (e >= n_edges) return;
    int s = esrc[e];
    int d = edst[e];
    float4 v = ((const float4*)(h + (size_t)s * D))[l];
    float* o = out + (size_t)d * D + (size_t)l * 4;
    atomicAdd(o + 0, v.x);
    atomicAdd(o + 1, v.y);
    atomicAdd(o + 2, v.z);
    atomicAdd(o + 3, v.w);
}

// ---------------- K2: in-place GEMM + bias + ReLU ----------------
// out[n,:] = relu(out[n,:] @ W^T + b). Row-local => in-place safe per block:
// each block stages its TM rows into LDS (sync) before overwriting them.
__global__ __launch_bounds__(256) void gemm_relu_kernel(
    float* __restrict__ io, const float* __restrict__ W,
    const float* __restrict__ b, int n_nodes)
{
    __shared__ float sA[TM * LDK];   // 33,792 B
    __shared__ float sW[D * LDK];    // 67,584 B  (total 101 KB -> 1 block/CU)
    const int tid = threadIdx.x;
    const int row0 = blockIdx.x * TM;

    // stage W [128x128] row-major (o,k), float4 per thread-iter
    for (int i = tid; i < D * D / 4; i += 256) {
        int o  = i >> 5;
        int k4 = i & 31;
        float4 w = ((const float4*)W)[i];
        *((float4*)&sW[o * LDK + k4 * 4]) = w;
    }
    // stage A tile [TM x 128]
    for (int i = tid; i < TM * D / 4; i += 256) {
        int r  = i >> 5;
        int k4 = i & 31;
        int gr = row0 + r;
        float4 a = make_float4(0.f, 0.f, 0.f, 0.f);
        if (gr < n_nodes) a = ((const float4*)io)[(size_t)gr * (D / 4) + k4];
        *((float4*)&sA[r * LDK + k4 * 4]) = a;
    }
    __syncthreads();

    const int rg = tid & 15;   // rows rg*4 .. rg*4+3
    const int cg = tid >> 4;   // cols cg*8 .. cg*8+7
    const int cx = cg & 3;     // per-wave xor swizzle -> conflict-free sW reads

    float acc[4][8];
    #pragma unroll
    for (int i = 0; i < 4; i++)
        #pragma unroll
        for (int j = 0; j < 8; j++) acc[i][j] = 0.f;

    #pragma unroll 4
    for (int k = 0; k < D; k += 4) {
        float4 a4[4], w4[8];
        #pragma unroll
        for (int i = 0; i < 4; i++)
            a4[i] = *((const float4*)&sA[(rg * 4 + i) * LDK + k]);
        #pragma unroll
        for (int j = 0; j < 8; j++) {
            int jj = j ^ cx;   // acc[i][j] accumulates col cg*8 + (j^cx)
            w4[j] = *((const float4*)&sW[(cg * 8 + jj) * LDK + k]);
        }
        #pragma unroll
        for (int i = 0; i < 4; i++)
            #pragma unroll
            for (int j = 0; j < 8; j++) {
                acc[i][j] = fmaf(a4[i].x, w4[j].x, acc[i][j]);
                acc[i][j] = fmaf(a4[i].y, w4[j].y, acc[i][j]);
                acc[i][j] = fmaf(a4[i].z, w4[j].z, acc[i][j]);
                acc[i][j] = fmaf(a4[i].w, w4[j].w, acc[i][j]);
            }
    }

    // bias for this thread's 8 contiguous cols
    float bb[8];
    #pragma unroll
    for (int j = 0; j < 8; j++) bb[j] = b[cg * 8 + j];

    #pragma unroll
    for (int i = 0; i < 4; i++) {
        int gr = row0 + rg * 4 + i;
        if (gr < n_nodes) {
            float vals[8];
            #pragma unroll
            for (int j = 0; j < 8; j++) {
                float vv = acc[i][j ^ cx] + bb[j];   // unswizzle: col cg*8+j
                vals[j] = vv > 0.f ? vv : 0.f;
            }
            float4* dst = (float4*)(io + (size_t)gr * D + cg * 8);
            dst[0] = make_float4(vals[0], vals[1], vals[2], vals[3]);
            dst[1] = make_float4(vals[4], vals[5], vals[6], vals[7]);
        }
    }
}

extern "C" void kernel_launch(void* const* d_in, const int* in_sizes, int n_in,
                              void* d_out, int out_size, void* d_ws, size_t ws_size,
                              hipStream_t stream) {
    const float* h    = (const float*)d_in[0];
    const int*   esrc = (const int*)d_in[1];
    const int*   edst = (const int*)d_in[2];
    const float* W    = (const float*)d_in[3];
    const float* b    = (const float*)d_in[4];
    float* out = (float*)d_out;
    const int n_nodes = in_sizes[0] / D;
    const int n_edges = in_sizes[1];

    // zero the accumulation target (harness re-poisons d_out each call)
    hipMemsetAsync(out, 0, (size_t)n_nodes * D * sizeof(float), stream);

    {   // scatter: 32 threads per edge
        long long total = (long long)n_edges * 32;
        int blocks = (int)((total + 255) / 256);
        scatter_kernel<<<blocks, 256, 0, stream>>>(h, esrc, edst, out, n_edges);
    }
    {   // in-place linear + bias + relu
        int blocks = (n_nodes + TM - 1) / TM;
        gemm_relu_kernel<<<blocks, 256, 0, stream>>>(out, W, b, n_nodes);
    }
}

// Round 2
// 549.014 us; speedup vs baseline: 5.3337x; 5.3337x over previous
//
#include <hip/hip_runtime.h>

#define D 128
#define TM 64
#define LDK 132   // 128 + 4 pad for sA/sW bank shift

// ================= CSR build =================

__global__ __launch_bounds__(256) void hist_kernel(
    const int* __restrict__ edst, int* __restrict__ cnt, int n_edges)
{
    int gid = blockIdx.x * 256 + threadIdx.x;
    if (gid < n_edges) atomicAdd(&cnt[edst[gid]], 1);
}

// per-block scan of 1024 elements (256 thr x 4), exclusive within block
__global__ __launch_bounds__(256) void scanA_kernel(
    const int* __restrict__ cnt, int* __restrict__ localoff,
    int* __restrict__ blocksums, int n)
{
    __shared__ int s[256];
    const int t = threadIdx.x;
    const int base = blockIdx.x * 1024 + t * 4;
    int v[4]; int sum = 0;
    #pragma unroll
    for (int i = 0; i < 4; i++) {
        int idx = base + i;
        v[i] = (idx < n) ? cnt[idx] : 0;
        sum += v[i];
    }
    s[t] = sum;
    __syncthreads();
    #pragma unroll
    for (int off = 1; off < 256; off <<= 1) {
        int x = (t >= off) ? s[t - off] : 0;
        __syncthreads();
        s[t] += x;
        __syncthreads();
    }
    int excl = s[t] - sum;  // exclusive prefix of this thread within block
    int run = 0;
    #pragma unroll
    for (int i = 0; i < 4; i++) {
        int idx = base + i;
        if (idx < n) localoff[idx] = excl + run;
        run += v[i];
    }
    if (t == 255) blocksums[blockIdx.x] = s[255];
}

// single-block exclusive scan of block sums (nb <= 256)
__global__ __launch_bounds__(256) void scanB_kernel(
    const int* __restrict__ blocksums, int* __restrict__ blockoffs, int nb)
{
    __shared__ int s[256];
    const int t = threadIdx.x;
    int v = (t < nb) ? blocksums[t] : 0;
    s[t] = v;
    __syncthreads();
    #pragma unroll
    for (int off = 1; off < 256; off <<= 1) {
        int x = (t >= off) ? s[t - off] : 0;
        __syncthreads();
        s[t] += x;
        __syncthreads();
    }
    if (t < nb) blockoffs[t] = s[t] - v;  // exclusive
}

// add block offsets; produce final offs[] and cursor[] copy
__global__ __launch_bounds__(256) void scanC_kernel(
    const int* __restrict__ localoff, const int* __restrict__ blockoffs,
    int* __restrict__ offs, int* __restrict__ cursor, int n)
{
    int gid = blockIdx.x * 256 + threadIdx.x;
    if (gid >= n) return;
    int v = localoff[gid] + blockoffs[blockIdx.x >> 2];  // 256-blk within 1024-blk
    offs[gid] = v;
    cursor[gid] = v;
}

__global__ __launch_bounds__(256) void place_kernel(
    const int* __restrict__ esrc, const int* __restrict__ edst,
    int* __restrict__ cursor, int* __restrict__ sorted_src, int n_edges)
{
    int gid = blockIdx.x * 256 + threadIdx.x;
    if (gid >= n_edges) return;
    int d = edst[gid];
    int pos = atomicAdd(&cursor[d], 1);
    sorted_src[pos] = esrc[gid];
}

// ================= gather aggregation =================
// 32 lanes per node (lane -> float4 of the 128-dim row); 8 nodes per block.
// After place_kernel, cursor[n] == offs[n] + deg[n], used as row end.
__global__ __launch_bounds__(256) void gather_kernel(
    const float* __restrict__ h, const int* __restrict__ offs,
    const int* __restrict__ endp, const int* __restrict__ sorted_src,
    float* __restrict__ out, int n_nodes)
{
    const int tid = threadIdx.x;
    const int node = blockIdx.x * 8 + (tid >> 5);
    const int lane = tid & 31;
    if (node >= n_nodes) return;
    const int start = offs[node];
    const int end = endp[node];
    const float4* __restrict__ h4 = (const float4*)h;
    float4 acc = make_float4(0.f, 0.f, 0.f, 0.f);
    int e = start;
    for (; e + 4 <= end; e += 4) {
        int s0 = sorted_src[e + 0];
        int s1 = sorted_src[e + 1];
        int s2 = sorted_src[e + 2];
        int s3 = sorted_src[e + 3];
        float4 a0 = h4[(size_t)s0 * 32 + lane];
        float4 a1 = h4[(size_t)s1 * 32 + lane];
        float4 a2 = h4[(size_t)s2 * 32 + lane];
        float4 a3 = h4[(size_t)s3 * 32 + lane];
        acc.x += a0.x + a1.x + a2.x + a3.x;
        acc.y += a0.y + a1.y + a2.y + a3.y;
        acc.z += a0.z + a1.z + a2.z + a3.z;
        acc.w += a0.w + a1.w + a2.w + a3.w;
    }
    for (; e < end; e++) {
        float4 a = h4[(size_t)sorted_src[e] * 32 + lane];
        acc.x += a.x; acc.y += a.y; acc.z += a.z; acc.w += a.w;
    }
    ((float4*)out)[(size_t)node * 32 + lane] = acc;
}

// ================= fallback: atomic scatter (round-1 path) =================
__global__ __launch_bounds__(256) void scatter_kernel(
    const float* __restrict__ h, const int* __restrict__ esrc,
    const int* __restrict__ edst, float* __restrict__ out, int n_edges)
{
    int gid = blockIdx.x * 256 + threadIdx.x;
    int e = gid >> 5;
    int l = gid & 31;
    if (e >= n_edges) return;
    int s = esrc[e];
    int d = edst[e];
    float4 v = ((const float4*)(h + (size_t)s * D))[l];
    float* o = out + (size_t)d * D + (size_t)l * 4;
    atomicAdd(o + 0, v.x);
    atomicAdd(o + 1, v.y);
    atomicAdd(o + 2, v.z);
    atomicAdd(o + 3, v.w);
}

// ================= in-place GEMM + bias + ReLU =================
__global__ __launch_bounds__(256) void gemm_relu_kernel(
    float* __restrict__ io, const float* __restrict__ W,
    const float* __restrict__ b, int n_nodes)
{
    __shared__ float sA[TM * LDK];
    __shared__ float sW[D * LDK];
    const int tid = threadIdx.x;
    const int row0 = blockIdx.x * TM;

    for (int i = tid; i < D * D / 4; i += 256) {
        int o  = i >> 5;
        int k4 = i & 31;
        float4 w = ((const float4*)W)[i];
        *((float4*)&sW[o * LDK + k4 * 4]) = w;
    }
    for (int i = tid; i < TM * D / 4; i += 256) {
        int r  = i >> 5;
        int k4 = i & 31;
        int gr = row0 + r;
        float4 a = make_float4(0.f, 0.f, 0.f, 0.f);
        if (gr < n_nodes) a = ((const float4*)io)[(size_t)gr * (D / 4) + k4];
        *((float4*)&sA[r * LDK + k4 * 4]) = a;
    }
    __syncthreads();

    const int rg = tid & 15;
    const int cg = tid >> 4;
    const int cx = cg & 3;

    float acc[4][8];
    #pragma unroll
    for (int i = 0; i < 4; i++)
        #pragma unroll
        for (int j = 0; j < 8; j++) acc[i][j] = 0.f;

    #pragma unroll 4
    for (int k = 0; k < D; k += 4) {
        float4 a4[4], w4[8];
        #pragma unroll
        for (int i = 0; i < 4; i++)
            a4[i] = *((const float4*)&sA[(rg * 4 + i) * LDK + k]);
        #pragma unroll
        for (int j = 0; j < 8; j++) {
            int jj = j ^ cx;
            w4[j] = *((const float4*)&sW[(cg * 8 + jj) * LDK + k]);
        }
        #pragma unroll
        for (int i = 0; i < 4; i++)
            #pragma unroll
            for (int j = 0; j < 8; j++) {
                acc[i][j] = fmaf(a4[i].x, w4[j].x, acc[i][j]);
                acc[i][j] = fmaf(a4[i].y, w4[j].y, acc[i][j]);
                acc[i][j] = fmaf(a4[i].z, w4[j].z, acc[i][j]);
                acc[i][j] = fmaf(a4[i].w, w4[j].w, acc[i][j]);
            }
    }

    float bb[8];
    #pragma unroll
    for (int j = 0; j < 8; j++) bb[j] = b[cg * 8 + j];

    #pragma unroll
    for (int i = 0; i < 4; i++) {
        int gr = row0 + rg * 4 + i;
        if (gr < n_nodes) {
            float vals[8];
            #pragma unroll
            for (int j = 0; j < 8; j++) {
                float vv = acc[i][j ^ cx] + bb[j];
                vals[j] = vv > 0.f ? vv : 0.f;
            }
            float4* dst = (float4*)(io + (size_t)gr * D + cg * 8);
            dst[0] = make_float4(vals[0], vals[1], vals[2], vals[3]);
            dst[1] = make_float4(vals[4], vals[5], vals[6], vals[7]);
        }
    }
}

extern "C" void kernel_launch(void* const* d_in, const int* in_sizes, int n_in,
                              void* d_out, int out_size, void* d_ws, size_t ws_size,
                              hipStream_t stream) {
    const float* h    = (const float*)d_in[0];
    const int*   esrc = (const int*)d_in[1];
    const int*   edst = (const int*)d_in[2];
    const float* W    = (const float*)d_in[3];
    const float* b    = (const float*)d_in[4];
    float* out = (float*)d_out;
    const int n_nodes = in_sizes[0] / D;
    const int n_edges = in_sizes[1];
    const int NB = (n_nodes + 1023) / 1024;   // scan blocks (<=256 required)

    // workspace layout (ints)
    size_t need = ((size_t)3 * n_nodes + 2 * NB + (size_t)n_edges) * sizeof(int);
    if (ws_size >= need && NB <= 256) {
        int* cnt        = (int*)d_ws;               // n_nodes (also localoff)
        int* offs       = cnt + n_nodes;            // n_nodes
        int* cursor     = offs + n_nodes;           // n_nodes
        int* blocksums  = cursor + n_nodes;         // NB
        int* blockoffs  = blocksums + NB;           // NB
        int* sorted_src = blockoffs + NB;           // n_edges

        hipMemsetAsync(cnt, 0, (size_t)n_nodes * sizeof(int), stream);
        hist_kernel<<<(n_edges + 255) / 256, 256, 0, stream>>>(edst, cnt, n_edges);
        // scan: cnt -> localoff (reuse cnt buffer in-place is unsafe; write into offs as scratch)
        scanA_kernel<<<NB, 256, 0, stream>>>(cnt, offs /*localoff scratch*/, blocksums, n_nodes);
        scanB_kernel<<<1, 256, 0, stream>>>(blocksums, blockoffs, NB);
        // finalize into cnt (reused as offs) + cursor
        scanC_kernel<<<(n_nodes + 255) / 256, 256, 0, stream>>>(offs, blockoffs, cnt, cursor, n_nodes);
        place_kernel<<<(n_edges + 255) / 256, 256, 0, stream>>>(esrc, edst, cursor, sorted_src, n_edges);
        // cursor[n] now == offs[n] + deg[n] -> row end
        gather_kernel<<<(n_nodes + 7) / 8, 256, 0, stream>>>(h, cnt, cursor, sorted_src, out, n_nodes);
    } else {
        // fallback: fp32 atomic scatter
        hipMemsetAsync(out, 0, (size_t)n_nodes * D * sizeof(float), stream);
        long long total = (long long)n_edges * 32;
        scatter_kernel<<<(int)((total + 255) / 256), 256, 0, stream>>>(h, esrc, edst, out, n_edges);
    }

    gemm_relu_kernel<<<(n_nodes + TM - 1) / TM, 256, 0, stream>>>(out, W, b, n_nodes);
}

// Round 3
// 402.761 us; speedup vs baseline: 7.2705x; 1.3631x over previous
//
#include <hip/hip_runtime.h>

#define D 128

typedef __attribute__((ext_vector_type(8))) short bf16x8;
typedef __attribute__((ext_vector_type(4))) float f32x4;

__device__ inline unsigned int pack2bf(float a, float b) {
    unsigned int ua = __float_as_uint(a);
    unsigned int ub = __float_as_uint(b);
    ua = (ua + 0x7fffu + ((ua >> 16) & 1u)) >> 16;   // RNE
    ub = (ub + 0x7fffu + ((ub >> 16) & 1u)) >> 16;
    return ua | (ub << 16);
}

// ================= CSR build =================

__global__ __launch_bounds__(256) void hist_kernel(
    const int* __restrict__ edst, int* __restrict__ cnt, int n_edges)
{
    int gid = blockIdx.x * 256 + threadIdx.x;
    if (gid < n_edges) atomicAdd(&cnt[edst[gid]], 1);
}

__global__ __launch_bounds__(256) void scanA_kernel(
    const int* __restrict__ cnt, int* __restrict__ localoff,
    int* __restrict__ blocksums, int n)
{
    __shared__ int s[256];
    const int t = threadIdx.x;
    const int base = blockIdx.x * 1024 + t * 4;
    int v[4]; int sum = 0;
    #pragma unroll
    for (int i = 0; i < 4; i++) {
        int idx = base + i;
        v[i] = (idx < n) ? cnt[idx] : 0;
        sum += v[i];
    }
    s[t] = sum;
    __syncthreads();
    #pragma unroll
    for (int off = 1; off < 256; off <<= 1) {
        int x = (t >= off) ? s[t - off] : 0;
        __syncthreads();
        s[t] += x;
        __syncthreads();
    }
    int excl = s[t] - sum;
    int run = 0;
    #pragma unroll
    for (int i = 0; i < 4; i++) {
        int idx = base + i;
        if (idx < n) localoff[idx] = excl + run;
        run += v[i];
    }
    if (t == 255) blocksums[blockIdx.x] = s[255];
}

__global__ __launch_bounds__(256) void scanB_kernel(
    const int* __restrict__ blocksums, int* __restrict__ blockoffs, int nb)
{
    __shared__ int s[256];
    const int t = threadIdx.x;
    int v = (t < nb) ? blocksums[t] : 0;
    s[t] = v;
    __syncthreads();
    #pragma unroll
    for (int off = 1; off < 256; off <<= 1) {
        int x = (t >= off) ? s[t - off] : 0;
        __syncthreads();
        s[t] += x;
        __syncthreads();
    }
    if (t < nb) blockoffs[t] = s[t] - v;
}

__global__ __launch_bounds__(256) void scanC_kernel(
    const int* __restrict__ localoff, const int* __restrict__ blockoffs,
    int* __restrict__ offs, int* __restrict__ cursor, int n)
{
    int gid = blockIdx.x * 256 + threadIdx.x;
    if (gid >= n) return;
    int v = localoff[gid] + blockoffs[blockIdx.x >> 2];
    offs[gid] = v;
    cursor[gid] = v;
}

__global__ __launch_bounds__(256) void place_kernel(
    const int* __restrict__ esrc, const int* __restrict__ edst,
    int* __restrict__ cursor, int* __restrict__ sorted_src, int n_edges)
{
    int gid = blockIdx.x * 256 + threadIdx.x;
    if (gid >= n_edges) return;
    int d = edst[gid];
    int pos = atomicAdd(&cursor[d], 1);
    sorted_src[pos] = esrc[gid];
}

// ================= h -> bf16 conversion =================
// each thread: one float4 -> uint2 (4 bf16)
__global__ __launch_bounds__(256) void h2bf_kernel(
    const float* __restrict__ h, uint2* __restrict__ hb, int n4)
{
    int gid = blockIdx.x * 256 + threadIdx.x;
    if (gid >= n4) return;
    float4 v = ((const float4*)h)[gid];
    hb[gid] = make_uint2(pack2bf(v.x, v.y), pack2bf(v.z, v.w));
}

// ================= gather (bf16 reads, fp32 acc, fp32 out) =================
__global__ __launch_bounds__(256) void gather_bf_kernel(
    const uint2* __restrict__ hb, const int* __restrict__ offs,
    const int* __restrict__ endp, const int* __restrict__ sorted_src,
    float* __restrict__ out, int n_nodes)
{
    const int tid = threadIdx.x;
    const int node = blockIdx.x * 8 + (tid >> 5);
    const int lane = tid & 31;
    if (node >= n_nodes) return;
    const int start = offs[node];
    const int end = endp[node];
    float4 acc = make_float4(0.f, 0.f, 0.f, 0.f);
    int e = start;
    for (; e + 4 <= end; e += 4) {
        int s0 = sorted_src[e + 0];
        int s1 = sorted_src[e + 1];
        int s2 = sorted_src[e + 2];
        int s3 = sorted_src[e + 3];
        uint2 v0 = hb[(size_t)s0 * 32 + lane];
        uint2 v1 = hb[(size_t)s1 * 32 + lane];
        uint2 v2 = hb[(size_t)s2 * 32 + lane];
        uint2 v3 = hb[(size_t)s3 * 32 + lane];
        acc.x += __uint_as_float(v0.x << 16) + __uint_as_float(v1.x << 16)
               + __uint_as_float(v2.x << 16) + __uint_as_float(v3.x << 16);
        acc.y += __uint_as_float(v0.x & 0xffff0000u) + __uint_as_float(v1.x & 0xffff0000u)
               + __uint_as_float(v2.x & 0xffff0000u) + __uint_as_float(v3.x & 0xffff0000u);
        acc.z += __uint_as_float(v0.y << 16) + __uint_as_float(v1.y << 16)
               + __uint_as_float(v2.y << 16) + __uint_as_float(v3.y << 16);
        acc.w += __uint_as_float(v0.y & 0xffff0000u) + __uint_as_float(v1.y & 0xffff0000u)
               + __uint_as_float(v2.y & 0xffff0000u) + __uint_as_float(v3.y & 0xffff0000u);
    }
    for (; e < end; e++) {
        uint2 v = hb[(size_t)sorted_src[e] * 32 + lane];
        acc.x += __uint_as_float(v.x << 16);
        acc.y += __uint_as_float(v.x & 0xffff0000u);
        acc.z += __uint_as_float(v.y << 16);
        acc.w += __uint_as_float(v.y & 0xffff0000u);
    }
    ((float4*)out)[(size_t)node * 32 + lane] = acc;
}

// ================= gather (fp32 fallback) =================
__global__ __launch_bounds__(256) void gather_kernel(
    const float* __restrict__ h, const int* __restrict__ offs,
    const int* __restrict__ endp, const int* __restrict__ sorted_src,
    float* __restrict__ out, int n_nodes)
{
    const int tid = threadIdx.x;
    const int node = blockIdx.x * 8 + (tid >> 5);
    const int lane = tid & 31;
    if (node >= n_nodes) return;
    const int start = offs[node];
    const int end = endp[node];
    const float4* __restrict__ h4 = (const float4*)h;
    float4 acc = make_float4(0.f, 0.f, 0.f, 0.f);
    int e = start;
    for (; e + 4 <= end; e += 4) {
        int s0 = sorted_src[e + 0];
        int s1 = sorted_src[e + 1];
        int s2 = sorted_src[e + 2];
        int s3 = sorted_src[e + 3];
        float4 a0 = h4[(size_t)s0 * 32 + lane];
        float4 a1 = h4[(size_t)s1 * 32 + lane];
        float4 a2 = h4[(size_t)s2 * 32 + lane];
        float4 a3 = h4[(size_t)s3 * 32 + lane];
        acc.x += a0.x + a1.x + a2.x + a3.x;
        acc.y += a0.y + a1.y + a2.y + a3.y;
        acc.z += a0.z + a1.z + a2.z + a3.z;
        acc.w += a0.w + a1.w + a2.w + a3.w;
    }
    for (; e < end; e++) {
        float4 a = h4[(size_t)sorted_src[e] * 32 + lane];
        acc.x += a.x; acc.y += a.y; acc.z += a.z; acc.w += a.w;
    }
    ((float4*)out)[(size_t)node * 32 + lane] = acc;
}

// ================= fallback: atomic scatter =================
__global__ __launch_bounds__(256) void scatter_kernel(
    const float* __restrict__ h, const int* __restrict__ esrc,
    const int* __restrict__ edst, float* __restrict__ out, int n_edges)
{
    int gid = blockIdx.x * 256 + threadIdx.x;
    int e = gid >> 5;
    int l = gid & 31;
    if (e >= n_edges) return;
    int s = esrc[e];
    int d = edst[e];
    float4 v = ((const float4*)(h + (size_t)s * D))[l];
    float* o = out + (size_t)d * D + (size_t)l * 4;
    atomicAdd(o + 0, v.x);
    atomicAdd(o + 1, v.y);
    atomicAdd(o + 2, v.z);
    atomicAdd(o + 3, v.w);
}

// ================= MFMA GEMM + bias + ReLU, in-place on io =================
// out[r,:] = relu(io[r,:] @ W^T + b). Each wave owns 16 rows: reads them
// (fp32 -> bf16 frags), computes 16x128 via mfma_f32_16x16x32_bf16, writes
// the same 16 rows. In-place safe per wave.
#define SW_LDU 68   // uints per W row in LDS (136 ushorts = 128 + 8 pad)

__global__ __launch_bounds__(256) void mfma_gemm_relu_kernel(
    float* __restrict__ io, const float* __restrict__ W,
    const float* __restrict__ b, int n_nodes)
{
    __shared__ unsigned int sW[128 * SW_LDU];  // 34,816 B
    const int tid = threadIdx.x;

    // stage W (fp32 [128 out][128 k]) -> bf16 in LDS, padded rows
    for (int i = tid; i < 4096; i += 256) {       // 4096 float4s
        float4 w = ((const float4*)W)[i];
        int row = i >> 5;                          // 32 float4 per row
        int c4  = i & 31;
        unsigned int* dst = &sW[row * SW_LDU + c4 * 2];
        dst[0] = pack2bf(w.x, w.y);
        dst[1] = pack2bf(w.z, w.w);
    }
    __syncthreads();

    const int wave = tid >> 6;
    const int lane = tid & 63;
    const int m = lane & 15;     // A-row / B-col within tile
    const int q = lane >> 4;     // quad
    const int r0 = blockIdx.x * 64 + wave * 16;
    const int arow = r0 + m;
    const bool rvalid = arow < n_nodes;

    // A fragments: 4 K-steps, lane holds A[arow][ks*32 + q*8 .. +7]
    bf16x8 afrag[4];
    #pragma unroll
    for (int ks = 0; ks < 4; ks++) {
        float4 x = make_float4(0.f,0.f,0.f,0.f), y = x;
        if (rvalid) {
            const float4* p = (const float4*)(io + (size_t)arow * D + ks * 32 + q * 8);
            x = p[0]; y = p[1];
        }
        union { unsigned int u[4]; bf16x8 v; } cvt;
        cvt.u[0] = pack2bf(x.x, x.y);
        cvt.u[1] = pack2bf(x.z, x.w);
        cvt.u[2] = pack2bf(y.x, y.y);
        cvt.u[3] = pack2bf(y.z, y.w);
        afrag[ks] = cvt.v;
    }

    f32x4 acc[8];
    #pragma unroll
    for (int ct = 0; ct < 8; ct++) acc[ct] = (f32x4){0.f, 0.f, 0.f, 0.f};

    #pragma unroll
    for (int ct = 0; ct < 8; ct++) {
        #pragma unroll
        for (int ks = 0; ks < 4; ks++) {
            // B[k][n] = W[ct*16+n][k]; lane: n=m, k = ks*32 + q*8 + j
            const unsigned int* p = &sW[(ct * 16 + m) * SW_LDU + ks * 16 + q * 4];
            union { uint4 u; bf16x8 v; } bu;
            bu.u = *(const uint4*)p;
            acc[ct] = __builtin_amdgcn_mfma_f32_16x16x32_bf16(afrag[ks], bu.v, acc[ct], 0, 0, 0);
        }
    }

    // epilogue: C[row=(q*4+i)][col=ct*16+m]
    #pragma unroll
    for (int ct = 0; ct < 8; ct++) {
        int col = ct * 16 + m;
        float bias = b[col];
        #pragma unroll
        for (int i = 0; i < 4; i++) {
            int r = r0 + q * 4 + i;
            if (r < n_nodes) {
                float v = acc[ct][i] + bias;
                io[(size_t)r * D + col] = v > 0.f ? v : 0.f;
            }
        }
    }
}

extern "C" void kernel_launch(void* const* d_in, const int* in_sizes, int n_in,
                              void* d_out, int out_size, void* d_ws, size_t ws_size,
                              hipStream_t stream) {
    const float* h    = (const float*)d_in[0];
    const int*   esrc = (const int*)d_in[1];
    const int*   edst = (const int*)d_in[2];
    const float* W    = (const float*)d_in[3];
    const float* b    = (const float*)d_in[4];
    float* out = (float*)d_out;
    const int n_nodes = in_sizes[0] / D;
    const int n_edges = in_sizes[1];
    const int NB = (n_nodes + 1023) / 1024;

    size_t csr_ints = (size_t)3 * n_nodes + 2 * NB + (size_t)n_edges;
    size_t needB = csr_ints * sizeof(int);
    size_t hb_off = (needB + 15) & ~(size_t)15;
    size_t needA = hb_off + (size_t)n_nodes * D * 2;   // + bf16 h copy

    if (ws_size >= needB && NB <= 256) {
        int* cnt        = (int*)d_ws;
        int* offs       = cnt + n_nodes;
        int* cursor     = offs + n_nodes;
        int* blocksums  = cursor + n_nodes;
        int* blockoffs  = blocksums + NB;
        int* sorted_src = blockoffs + NB;

        hipMemsetAsync(cnt, 0, (size_t)n_nodes * sizeof(int), stream);
        hist_kernel<<<(n_edges + 255) / 256, 256, 0, stream>>>(edst, cnt, n_edges);
        scanA_kernel<<<NB, 256, 0, stream>>>(cnt, offs, blocksums, n_nodes);
        scanB_kernel<<<1, 256, 0, stream>>>(blocksums, blockoffs, NB);
        scanC_kernel<<<(n_nodes + 255) / 256, 256, 0, stream>>>(offs, blockoffs, cnt, cursor, n_nodes);
        place_kernel<<<(n_edges + 255) / 256, 256, 0, stream>>>(esrc, edst, cursor, sorted_src, n_edges);

        if (ws_size >= needA) {
            uint2* hb = (uint2*)((char*)d_ws + hb_off);
            int n4 = n_nodes * (D / 4);
            h2bf_kernel<<<(n4 + 255) / 256, 256, 0, stream>>>(h, hb, n4);
            gather_bf_kernel<<<(n_nodes + 7) / 8, 256, 0, stream>>>(
                hb, cnt, cursor, sorted_src, out, n_nodes);
        } else {
            gather_kernel<<<(n_nodes + 7) / 8, 256, 0, stream>>>(
                h, cnt, cursor, sorted_src, out, n_nodes);
        }
    } else {
        hipMemsetAsync(out, 0, (size_t)n_nodes * D * sizeof(float), stream);
        long long total = (long long)n_edges * 32;
        scatter_kernel<<<(int)((total + 255) / 256), 256, 0, stream>>>(h, esrc, edst, out, n_edges);
    }

    mfma_gemm_relu_kernel<<<(n_nodes + 63) / 64, 256, 0, stream>>>(out, W, b, n_nodes);
}